// Round 16
// baseline (217.423 us; speedup 1.0000x reference)
//
#include <hip/hip_runtime.h>
#include <hip/hip_bf16.h>
#include <math.h>

#define NEG_SLOPE 0.2f
#define EPS_SM 1e-16f
#define BN_EPS 1e-5f
#define CHUNKS 256  // coarse-pass blocks

typedef __attribute__((ext_vector_type(8))) short bf16x8;
typedef __attribute__((ext_vector_type(4))) float f32x4;

__device__ __forceinline__ float lrelu(float x) { return x > 0.f ? x : NEG_SLOPE * x; }
// fp32 -> bf16 round-to-nearest-even
__device__ __forceinline__ ushort f2bf(float f) {
    uint u = __float_as_uint(f);
    return (ushort)((u + 0x7FFFu + ((u >> 16) & 1u)) >> 16);
}
__device__ __forceinline__ float bfl(uint u) { return __uint_as_float(u << 16); }
__device__ __forceinline__ float bfh(uint u) { return __uint_as_float(u & 0xFFFF0000u); }

// ---- pack W fp32 -> bf16 in B-fragment order; also zeros BN sums ----
__global__ void pack_w(const float* __restrict__ W0, const float* __restrict__ W1,
                       const float* __restrict__ W2, ushort* __restrict__ P0,
                       ushort* __restrict__ P1, ushort* __restrict__ P2,
                       float* __restrict__ sums) {
    int i = blockIdx.x * blockDim.x + threadIdx.x;
    if (i < 8192) sums[i] = 0.f;  // sumsP0 + sumsP1 (contiguous)
    const float* W;
    ushort* P;
    int NC, s;
    if (i < 16384) { W = W0; P = P0; NC = 128; s = i; }
    else if (i < 32768) { W = W1; P = P1; NC = 128; s = i - 16384; }
    else if (i < 34816) { W = W2; P = P2; NC = 16; s = i - 32768; }
    else return;
    int k = s / NC, col = s % NC;
    int CT = NC >> 4;
    int dst = (((k >> 5) * CT + (col >> 4)) << 9) +
              (((col & 15) | (((k >> 3) & 3) << 4)) << 3) + (k & 7);
    P[dst] = f2bf(W[s]);
}

// ================= zero-device-atomic CSR build =================
__global__ __launch_bounds__(256) void bucket_scatter(const int* __restrict__ src,
                                                      const int* __restrict__ dst, int E,
                                                      const int* __restrict__ base,
                                                      uint* __restrict__ bpack, int nbuck) {
    __shared__ int cur[256];
    int blk = blockIdx.x, tid = threadIdx.x;
    if (tid < nbuck) cur[tid] = base[tid * CHUNKS + blk];
    __syncthreads();
    int e0 = (int)(((long)E * blk) >> 8);
    int e1 = (int)(((long)E * (blk + 1)) >> 8);
    for (int i = e0 + tid; i < e1; i += 256) {
        int d = dst[i];
        int p = atomicAdd(&cur[d >> 8], 1);
        bpack[p] = ((uint)src[i] << 8) | (uint)(d & 255);
    }
}

__global__ __launch_bounds__(256) void fine_csr(const uint* __restrict__ bpack,
                                                const int* __restrict__ base, int E, int n,
                                                int* __restrict__ offs, int* __restrict__ srcs,
                                                int nbuck) {
    __shared__ int cnt[256];
    __shared__ int wsum[4];
    int bk = blockIdx.x, tid = threadIdx.x;
    int ebase = base[bk * CHUNKS];
    int eend = base[(bk + 1) * CHUNKS];
    cnt[tid] = 0;
    __syncthreads();
    for (int i = ebase + tid; i < eend; i += 256) atomicAdd(&cnt[bpack[i] & 255], 1);
    __syncthreads();
    int lane = tid & 63, w = tid >> 6;
    int v = cnt[tid];
    int incl = v;
#pragma unroll
    for (int d = 1; d < 64; d <<= 1) {
        int t = __shfl_up(incl, d, 64);
        if (lane >= d) incl += t;
    }
    if (lane == 63) wsum[w] = incl;
    __syncthreads();
    int wbase = 0;
    for (int j = 0; j < w; ++j) wbase += wsum[j];
    int excl = wbase + incl - v;
    int node = bk * 256 + tid;
    if (node < n) offs[node] = ebase + excl;
    cnt[tid] = ebase + excl;  // reuse as cursor
    __syncthreads();
    for (int i = ebase + tid; i < eend; i += 256) {
        uint pk = bpack[i];
        int p = atomicAdd(&cnt[pk & 255], 1);
        srcs[p] = (int)(pk >> 8);
    }
    if (bk == nbuck - 1 && tid == 0) offs[n] = E;
}

// ---- MFMA GEMM: 16 rows/block, ONE wave/block. B-frags from global (L1-hot).
// ---- Node-major h + scores. Optional bf16-X + fused BN+ELU staging; optional
// ---- coarse bucket histogram fused in leading CHUNKS blocks.
template <int NC, int HEADS, bool XBN, bool BCFUSE>
__global__ __launch_bounds__(64) void gemm_mfma(
    const void* __restrict__ Xv, const ushort* __restrict__ Wp, ushort* __restrict__ Hb,
    int n, const float* __restrict__ sumsP, const float* __restrict__ g,
    const float* __restrict__ be, const float* __restrict__ as_, const float* __restrict__ ad_,
    float* __restrict__ ss, float* __restrict__ sd,
    const int* __restrict__ dstE, int E, int* __restrict__ hist, int nbuck) {
    int tid = threadIdx.x;
    constexpr int CT = NC / 16;
    constexpr int FPH = NC / HEADS / 16;
    __shared__ __align__(16) ushort Xb[16 * 128];
    __shared__ float ssl[16 * HEADS], sdl[16 * HEADS];
    if constexpr (BCFUSE) {
        if ((int)blockIdx.x < CHUNKS) {  // coarse histogram, LDS atomics only
            int* h = (int*)Xb;
            for (int j = tid; j < 256; j += 64) h[j] = 0;
            __syncthreads();
            int blk = blockIdx.x;
            int e0 = (int)(((long)E * blk) >> 8);
            int e1 = (int)(((long)E * (blk + 1)) >> 8);
            for (int i = e0 + tid; i < e1; i += 64) atomicAdd(&h[dstE[i] >> 8], 1);
            __syncthreads();
            for (int j = tid; j < nbuck; j += 64) hist[j * CHUNKS + blk] = h[j];
            return;
        }
    }
    int bid = BCFUSE ? ((int)blockIdx.x - CHUNKS) : (int)blockIdx.x;
    int row0 = bid * 16;
    if constexpr (!XBN) {
        const float* X = (const float*)Xv;
#pragma unroll
        for (int i = 0; i < 8; ++i) {
            int idx = tid + i * 64;
            int row = idx >> 5, q = idx & 31;
            int gr = row0 + row;
            float4 v = make_float4(0.f, 0.f, 0.f, 0.f);
            if (gr < n) v = ((const float4*)(X + (long)gr * 128))[q];
            ushort4 p = make_ushort4(f2bf(v.x), f2bf(v.y), f2bf(v.z), f2bf(v.w));
            int s = (q >> 1) ^ (row & 15);
            *(ushort4*)&Xb[row * 128 + s * 8 + (q & 1) * 4] = p;
        }
    } else {
        const ushort* X = (const ushort*)Xv;
        int c8 = (tid & 15) * 8;
        float inv_n = 1.f / (float)n;
        float bm[8], bs[8], bb[8];
#pragma unroll
        for (int j = 0; j < 8; ++j) {
            int ch = c8 + j;
            float m = sumsP[ch * 16] * inv_n;
            float vv = fmaxf(sumsP[(128 + ch) * 16] * inv_n - m * m, 0.f);
            bm[j] = m;
            bs[j] = rsqrtf(vv + BN_EPS) * g[ch];
            bb[j] = be[ch];
        }
#pragma unroll
        for (int i = 0; i < 4; ++i) {
            int idx = tid + i * 64;
            int row = idx >> 4, g8 = idx & 15;
            int gr = row0 + row;
            uint4 v = make_uint4(0, 0, 0, 0);
            if (gr < n) v = ((const uint4*)(X + (long)gr * 128))[g8];
            float a, b;
#define BNE(comp, j0)                                                  \
    a = bfl(comp); b = bfh(comp);                                      \
    a = (a - bm[j0]) * bs[j0] + bb[j0]; a = a > 0.f ? a : expm1f(a);   \
    b = (b - bm[j0 + 1]) * bs[j0 + 1] + bb[j0 + 1];                    \
    b = b > 0.f ? b : expm1f(b);                                       \
    comp = (uint)f2bf(a) | ((uint)f2bf(b) << 16);
            BNE(v.x, 0) BNE(v.y, 2) BNE(v.z, 4) BNE(v.w, 6)
#undef BNE
            int s = g8 ^ (row & 15);
            *(uint4*)&Xb[row * 128 + s * 8] = v;
        }
    }
    __syncthreads();
    int lane = tid;
    int lrow = lane & 15, lhi = lane >> 4;
    f32x4 zero = {0.f, 0.f, 0.f, 0.f};
    f32x4 acc[CT];
#pragma unroll
    for (int f = 0; f < CT; ++f) acc[f] = zero;
    const ushort* xr = &Xb[lrow * 128];
#pragma unroll
    for (int ks = 0; ks < 4; ++ks) {
        int kg = ks * 4 + lhi;
        bf16x8 a = *(const bf16x8*)&xr[(kg ^ lrow) << 3];
#pragma unroll
        for (int f = 0; f < CT; ++f) {
            bf16x8 b = *(const bf16x8*)&Wp[((ks * CT + f) * 64 + lane) * 8];
            acc[f] = __builtin_amdgcn_mfma_f32_16x16x32_bf16(a, b, acc[f], 0, 0, 0);
        }
    }
    __syncthreads();
#pragma unroll
    for (int f = 0; f < CT; ++f)
#pragma unroll
        for (int j = 0; j < 4; ++j)
            Xb[(lhi * 4 + j) * NC + f * 16 + lrow] = f2bf(acc[f][j]);
    float asv[CT], adv[CT];
#pragma unroll
    for (int f = 0; f < CT; ++f) {
        asv[f] = as_[f * 16 + lrow];
        adv[f] = ad_[f * 16 + lrow];
    }
#pragma unroll
    for (int h = 0; h < HEADS; ++h) {
        float ps[4] = {}, pd[4] = {};
#pragma unroll
        for (int fi = 0; fi < FPH; ++fi) {
            int f = h * FPH + fi;
#pragma unroll
            for (int j = 0; j < 4; ++j) {
                ps[j] = fmaf(acc[f][j], asv[f], ps[j]);
                pd[j] = fmaf(acc[f][j], adv[f], pd[j]);
            }
        }
#pragma unroll
        for (int j = 0; j < 4; ++j) {
#pragma unroll
            for (int d = 1; d < 16; d <<= 1) {
                ps[j] += __shfl_xor(ps[j], d, 64);
                pd[j] += __shfl_xor(pd[j], d, 64);
            }
            if (lrow == 0) {
                ssl[(lhi * 4 + j) * HEADS + h] = ps[j];
                sdl[(lhi * 4 + j) * HEADS + h] = pd[j];
            }
        }
    }
    __syncthreads();
    constexpr int NU = 16 * NC / 8;
#pragma unroll
    for (int i = 0; i < (NU + 63) / 64; ++i) {
        int idx = tid + i * 64;
        if (idx < NU) {
            int row = idx / (NC / 8), c8i = idx % (NC / 8);
            int gr = row0 + row;
            if (gr < n) ((uint4*)&Hb[(long)gr * NC])[c8i] = ((const uint4*)Xb)[idx];
        }
    }
    if (tid < 16 * HEADS) {
        int row = tid / HEADS, hh = tid % HEADS;
        int gr = row0 + row;
        if (gr < n) {
            ss[(long)gr * HEADS + hh] = ssl[tid];
            sd[(long)gr * HEADS + hh] = sdl[tid];
        }
    }
}

// ---------------- generic single-block int4 scan (+ sentinel at [n]) ----------------
__global__ __launch_bounds__(1024) void scan_kernel(const int* __restrict__ deg,
                                                    int* __restrict__ offs, int n) {
    __shared__ int wsum[16];
    __shared__ int wpre[16];
    __shared__ int carry_s;
    int tid = threadIdx.x;
    int lane = tid & 63;
    int w = tid >> 6;
    if (tid == 0) carry_s = 0;
    __syncthreads();
    int nv = (n + 3) >> 2;
    for (int base = 0; base < nv; base += 1024) {
        int carry = carry_s;
        int gi = base + tid;
        int e0 = gi * 4;
        int4 v = make_int4(0, 0, 0, 0);
        if (e0 + 3 < n) {
            v = ((const int4*)deg)[gi];
        } else if (e0 < n) {
            v.x = deg[e0];
            if (e0 + 1 < n) v.y = deg[e0 + 1];
            if (e0 + 2 < n) v.z = deg[e0 + 2];
        }
        int tsum = v.x + v.y + v.z + v.w;
        int incl = tsum;
#pragma unroll
        for (int d = 1; d < 64; d <<= 1) {
            int t = __shfl_up(incl, d, 64);
            if (lane >= d) incl += t;
        }
        if (lane == 63) wsum[w] = incl;
        __syncthreads();
        if (w == 0 && lane < 16) {
            int s = wsum[lane];
#pragma unroll
            for (int d = 1; d < 16; d <<= 1) {
                int t = __shfl_up(s, d, 64);
                if (lane >= d) s += t;
            }
            wpre[lane] = s;
        }
        __syncthreads();
        int wbase = (w == 0) ? 0 : wpre[w - 1];
        int ex = carry + wbase + incl - tsum;
        if (e0 < n) {
            int4 o;
            o.x = ex;
            o.y = ex + v.x;
            o.z = o.y + v.y;
            o.w = o.z + v.z;
            if (e0 + 3 < n) {
                ((int4*)offs)[gi] = o;
            } else {
                offs[e0] = o.x;
                if (e0 + 1 < n) offs[e0 + 1] = o.y;
                if (e0 + 2 < n) offs[e0 + 2] = o.z;
            }
        }
        __syncthreads();
        if (tid == 1023) carry_s = carry + wpre[15];
        __syncthreads();
    }
    if (tid == 0) offs[n] = carry_s;
}

// ---- GAT gather, 4 heads x 32ch: 4 edge-groups x 16 lanes x 8ch,
// ---- QUAD-unrolled edge loop (16 edges / 4KB of h-rows in flight per wave —
// ---- deg~17 becomes ONE latency exposure).
__global__ __launch_bounds__(256) void gat_gather4(
    const uint* __restrict__ hb, const float* __restrict__ ss, const float* __restrict__ sd,
    const int* __restrict__ offs, const int* __restrict__ srcs,
    const float* __restrict__ bias, ushort* __restrict__ outb, int n) {
    int wid = threadIdx.x >> 6;
    int lane = threadIdx.x & 63;
    int node = blockIdx.x * 4 + wid;
    if (node >= n) return;
    int off = offs[node];
    int dg = offs[node + 1] - off;
    int grp = lane >> 4;
    int ll = lane & 15;
    int hd = ll >> 2;
    float sdn = sd[node * 4 + hd];
    float es = lrelu(ss[node * 4 + hd] + sdn);
    const uint* hrow = hb + ll * 4;
    float acc[8] = {};
    float sm = 0.f;
    int i = grp;
#define EDGE(sv, wv, hv)                                   \
    {                                                      \
        sm += wv;                                          \
        acc[0] = fmaf(wv, bfl(hv.x), acc[0]);              \
        acc[1] = fmaf(wv, bfh(hv.x), acc[1]);              \
        acc[2] = fmaf(wv, bfl(hv.y), acc[2]);              \
        acc[3] = fmaf(wv, bfh(hv.y), acc[3]);              \
        acc[4] = fmaf(wv, bfl(hv.z), acc[4]);              \
        acc[5] = fmaf(wv, bfh(hv.z), acc[5]);              \
        acc[6] = fmaf(wv, bfl(hv.w), acc[6]);              \
        acc[7] = fmaf(wv, bfh(hv.w), acc[7]);              \
    }
    for (; i + 12 < dg; i += 16) {  // quad: 4 edges per group in flight
        int s0 = srcs[off + i];
        int s1 = srcs[off + i + 4];
        int s2 = srcs[off + i + 8];
        int s3 = srcs[off + i + 12];
        float w0 = __expf(lrelu(ss[s0 * 4 + hd] + sdn));
        float w1 = __expf(lrelu(ss[s1 * 4 + hd] + sdn));
        float w2 = __expf(lrelu(ss[s2 * 4 + hd] + sdn));
        float w3 = __expf(lrelu(ss[s3 * 4 + hd] + sdn));
        uint4 h0 = *(const uint4*)(hrow + (long)s0 * 64);
        uint4 h1 = *(const uint4*)(hrow + (long)s1 * 64);
        uint4 h2 = *(const uint4*)(hrow + (long)s2 * 64);
        uint4 h3 = *(const uint4*)(hrow + (long)s3 * 64);
        EDGE(s0, w0, h0) EDGE(s1, w1, h1) EDGE(s2, w2, h2) EDGE(s3, w3, h3)
    }
    for (; i + 4 < dg; i += 8) {  // pair remainder
        int s0 = srcs[off + i];
        int s1 = srcs[off + i + 4];
        float w0 = __expf(lrelu(ss[s0 * 4 + hd] + sdn));
        float w1 = __expf(lrelu(ss[s1 * 4 + hd] + sdn));
        uint4 h0 = *(const uint4*)(hrow + (long)s0 * 64);
        uint4 h1 = *(const uint4*)(hrow + (long)s1 * 64);
        EDGE(s0, w0, h0) EDGE(s1, w1, h1)
    }
    for (; i < dg; i += 4) {  // single remainder
        int s = srcs[off + i];
        float w = __expf(lrelu(ss[s * 4 + hd] + sdn));
        uint4 hv = *(const uint4*)(hrow + (long)s * 64);
        EDGE(s, w, hv)
    }
#undef EDGE
#pragma unroll
    for (int j = 0; j < 8; ++j) {
        acc[j] += __shfl_xor(acc[j], 16, 64);
        acc[j] += __shfl_xor(acc[j], 32, 64);
    }
    sm += __shfl_xor(sm, 16, 64);
    sm += __shfl_xor(sm, 32, 64);
    float wS = __expf(es);
    sm += wS;
    uint4 hvS = *(const uint4*)(hrow + (long)node * 64);
    acc[0] = fmaf(wS, bfl(hvS.x), acc[0]);
    acc[1] = fmaf(wS, bfh(hvS.x), acc[1]);
    acc[2] = fmaf(wS, bfl(hvS.y), acc[2]);
    acc[3] = fmaf(wS, bfh(hvS.y), acc[3]);
    acc[4] = fmaf(wS, bfl(hvS.z), acc[4]);
    acc[5] = fmaf(wS, bfh(hvS.z), acc[5]);
    acc[6] = fmaf(wS, bfl(hvS.w), acc[6]);
    acc[7] = fmaf(wS, bfh(hvS.w), acc[7]);
    float inv = 1.f / (sm + EPS_SM);
    if (grp == 0) {
        float4 bA = *(const float4*)&bias[ll * 8];
        float4 bB = *(const float4*)&bias[ll * 8 + 4];
        uint4 p;
        p.x = (uint)f2bf(acc[0] * inv + bA.x) | ((uint)f2bf(acc[1] * inv + bA.y) << 16);
        p.y = (uint)f2bf(acc[2] * inv + bA.z) | ((uint)f2bf(acc[3] * inv + bA.w) << 16);
        p.z = (uint)f2bf(acc[4] * inv + bB.x) | ((uint)f2bf(acc[5] * inv + bB.y) << 16);
        p.w = (uint)f2bf(acc[6] * inv + bB.z) | ((uint)f2bf(acc[7] * inv + bB.w) << 16);
        *(uint4*)&outb[(long)node * 128 + ll * 8] = p;
    }
}

// ---- GAT gather, 1 head x 16ch: 16 edge-groups x 4 lanes x 4ch (uint2),
// ---- pair-unrolled (32 edges in flight per wave).
__global__ __launch_bounds__(256) void gat_gather1(
    const uint* __restrict__ hb2, const float* __restrict__ ss, const float* __restrict__ sd,
    const int* __restrict__ offs, const int* __restrict__ srcs,
    const float* __restrict__ bias, float* __restrict__ out, int n) {
    int wid = threadIdx.x >> 6;
    int lane = threadIdx.x & 63;
    int node = blockIdx.x * 4 + wid;
    if (node >= n) return;
    int off = offs[node];
    int dg = offs[node + 1] - off;
    int grp = lane >> 2;  // 16 edge groups
    int ll = lane & 3;    // channels ll*4 .. ll*4+3
    float sdn = sd[node];
    float es = lrelu(ss[node] + sdn);
    float acc[4] = {};
    float sm = 0.f;
    int i = grp;
    for (; i + 16 < dg; i += 32) {  // pair: 2 edges per group in flight
        int s0 = srcs[off + i];
        int s1 = srcs[off + i + 16];
        float w0 = __expf(lrelu(ss[s0] + sdn));
        float w1 = __expf(lrelu(ss[s1] + sdn));
        uint2 h0 = *(const uint2*)(hb2 + s0 * 8 + ll * 2);
        uint2 h1 = *(const uint2*)(hb2 + s1 * 8 + ll * 2);
        sm += w0 + w1;
        acc[0] = fmaf(w0, bfl(h0.x), acc[0]); acc[0] = fmaf(w1, bfl(h1.x), acc[0]);
        acc[1] = fmaf(w0, bfh(h0.x), acc[1]); acc[1] = fmaf(w1, bfh(h1.x), acc[1]);
        acc[2] = fmaf(w0, bfl(h0.y), acc[2]); acc[2] = fmaf(w1, bfl(h1.y), acc[2]);
        acc[3] = fmaf(w0, bfh(h0.y), acc[3]); acc[3] = fmaf(w1, bfh(h1.y), acc[3]);
    }
    for (; i < dg; i += 16) {
        int s = srcs[off + i];
        float w = __expf(lrelu(ss[s] + sdn));
        uint2 hv = *(const uint2*)(hb2 + s * 8 + ll * 2);
        sm += w;
        acc[0] = fmaf(w, bfl(hv.x), acc[0]);
        acc[1] = fmaf(w, bfh(hv.x), acc[1]);
        acc[2] = fmaf(w, bfl(hv.y), acc[2]);
        acc[3] = fmaf(w, bfh(hv.y), acc[3]);
    }
#pragma unroll
    for (int j = 0; j < 4; ++j) {
        acc[j] += __shfl_xor(acc[j], 4, 64);
        acc[j] += __shfl_xor(acc[j], 8, 64);
        acc[j] += __shfl_xor(acc[j], 16, 64);
        acc[j] += __shfl_xor(acc[j], 32, 64);
    }
    sm += __shfl_xor(sm, 4, 64);
    sm += __shfl_xor(sm, 8, 64);
    sm += __shfl_xor(sm, 16, 64);
    sm += __shfl_xor(sm, 32, 64);
    float wS = __expf(es);
    sm += wS;
    uint2 hvS = *(const uint2*)(hb2 + node * 8 + ll * 2);
    acc[0] = fmaf(wS, bfl(hvS.x), acc[0]);
    acc[1] = fmaf(wS, bfh(hvS.x), acc[1]);
    acc[2] = fmaf(wS, bfl(hvS.y), acc[2]);
    acc[3] = fmaf(wS, bfh(hvS.y), acc[3]);
    float inv = 1.f / (sm + EPS_SM);
    if (grp == 0) {
        float4 b4 = *(const float4*)&bias[ll * 4];
        float4 o = make_float4(acc[0] * inv + b4.x, acc[1] * inv + b4.y,
                               acc[2] * inv + b4.z, acc[3] * inv + b4.w);
        *(float4*)&out[(long)node * 16 + ll * 4] = o;
    }
}

// ---- BatchNorm stats (bf16 input) ----
__global__ __launch_bounds__(256) void bn_stats_bf16(const uint4* __restrict__ X4,
                                                     float* __restrict__ sumsP, int n) {
    __shared__ float red[4096];
    int tid = threadIdx.x;
    float s[8] = {}, s2[8] = {};
    long tot = (long)n * 16;
    long T = (long)gridDim.x * 256;
    for (long i = (long)blockIdx.x * 256 + tid; i < tot; i += T) {
        uint4 v = X4[i];
        float f;
        f = bfl(v.x); s[0] += f; s2[0] = fmaf(f, f, s2[0]);
        f = bfh(v.x); s[1] += f; s2[1] = fmaf(f, f, s2[1]);
        f = bfl(v.y); s[2] += f; s2[2] = fmaf(f, f, s2[2]);
        f = bfh(v.y); s[3] += f; s2[3] = fmaf(f, f, s2[3]);
        f = bfl(v.z); s[4] += f; s2[4] = fmaf(f, f, s2[4]);
        f = bfh(v.z); s[5] += f; s2[5] = fmaf(f, f, s2[5]);
        f = bfl(v.w); s[6] += f; s2[6] = fmaf(f, f, s2[6]);
        f = bfh(v.w); s[7] += f; s2[7] = fmaf(f, f, s2[7]);
    }
#pragma unroll
    for (int j = 0; j < 8; ++j) {
        red[j * 256 + tid] = s[j];
        red[(8 + j) * 256 + tid] = s2[j];
    }
    __syncthreads();
    int ch = tid & 127, st = tid >> 7;
    int base = (st * 8 + (ch & 7)) * 256 + (ch >> 3);
    float a = 0.f;
#pragma unroll
    for (int rep = 0; rep < 16; ++rep) a += red[base + rep * 16];
    atomicAdd(&sumsP[tid * 16], a);
}

extern "C" void kernel_launch(void* const* d_in, const int* in_sizes, int n_in,
                              void* d_out, int out_size, void* d_ws, size_t ws_size,
                              hipStream_t stream) {
    const float* x = (const float*)d_in[0];
    const int* ei = (const int*)d_in[1];
    const float* W0 = (const float*)d_in[2];
    const float* as0 = (const float*)d_in[3];
    const float* ad0 = (const float*)d_in[4];
    const float* b0 = (const float*)d_in[5];
    const float* g0 = (const float*)d_in[6];
    const float* be0 = (const float*)d_in[7];
    const float* W1 = (const float*)d_in[8];
    const float* as1 = (const float*)d_in[9];
    const float* ad1 = (const float*)d_in[10];
    const float* b1 = (const float*)d_in[11];
    const float* g1 = (const float*)d_in[12];
    const float* be1 = (const float*)d_in[13];
    const float* W2 = (const float*)d_in[14];
    const float* as2 = (const float*)d_in[15];
    const float* ad2 = (const float*)d_in[16];
    const float* b2 = (const float*)d_in[17];

    int n = in_sizes[0] / 128;
    int E = in_sizes[1] / 2;
    const int* srcA = ei;
    const int* dstA = ei + E;
    int nbuck = (n + 255) >> 8;

    char* base = (char*)d_ws;
    auto alloc = [&](size_t bytes) {
        char* p = base;
        base += (bytes + 255) & ~(size_t)255;
        return p;
    };
    ushort* hb = (ushort*)alloc((size_t)n * 128 * 2);
    ushort* actb = (ushort*)alloc((size_t)n * 128 * 2);
    ushort* h2b = (ushort*)alloc((size_t)n * 16 * 2);
    float* ssb = (float*)alloc((size_t)n * 4 * 4);
    float* sdb = (float*)alloc((size_t)n * 4 * 4);
    float* sumsP0 = (float*)alloc(4096 * 4);
    float* sumsP1 = (float*)alloc(4096 * 4);
    int* hist = (int*)alloc(((size_t)nbuck * CHUNKS + 1) * 4);
    int* bbase = (int*)alloc(((size_t)nbuck * CHUNKS + 1) * 4);
    uint* bpack = (uint*)alloc((size_t)E * 4);
    int* offs = (int*)alloc(((size_t)n + 1) * 4);
    int* srcs = (int*)alloc((size_t)E * 4);
    ushort* Wp0 = (ushort*)alloc(16384 * 2);
    ushort* Wp1 = (ushort*)alloc(16384 * 2);
    ushort* Wp2 = (ushort*)alloc(2048 * 2);

    float* out = (float*)d_out;

    pack_w<<<136, 256, 0, stream>>>(W0, W1, W2, Wp0, Wp1, Wp2, sumsP0);

    int gGemm = (n + 15) / 16;
    int gWave = (n + 3) / 4;

    // ---- layer 0 GEMM (fp32 X) + fused coarse bucket histogram ----
    gemm_mfma<128, 4, false, true><<<CHUNKS + gGemm, 64, 0, stream>>>(
        x, Wp0, hb, n, nullptr, g0, be0, as0, ad0, ssb, sdb, dstA, E, hist, nbuck);
    scan_kernel<<<1, 1024, 0, stream>>>(hist, bbase, nbuck * CHUNKS);
    bucket_scatter<<<CHUNKS, 256, 0, stream>>>(srcA, dstA, E, bbase, bpack, nbuck);
    fine_csr<<<nbuck, 256, 0, stream>>>(bpack, bbase, E, n, offs, srcs, nbuck);

    gat_gather4<<<gWave, 256, 0, stream>>>((const uint*)hb, ssb, sdb, offs, srcs, b0, actb, n);
    bn_stats_bf16<<<256, 256, 0, stream>>>((const uint4*)actb, sumsP0, n);

    // ---- layer 1 (BN+ELU fused into bf16 GEMM staging) ----
    gemm_mfma<128, 4, true, false><<<gGemm, 64, 0, stream>>>(
        actb, Wp1, hb, n, sumsP0, g0, be0, as1, ad1, ssb, sdb, nullptr, 0, nullptr, 0);
    gat_gather4<<<gWave, 256, 0, stream>>>((const uint*)hb, ssb, sdb, offs, srcs, b1, actb, n);
    bn_stats_bf16<<<256, 256, 0, stream>>>((const uint4*)actb, sumsP1, n);

    // ---- layer 2 ----
    gemm_mfma<16, 1, true, false><<<gGemm, 64, 0, stream>>>(
        actb, Wp2, h2b, n, sumsP1, g1, be1, as2, ad2, ssb, sdb, nullptr, 0, nullptr, 0);
    gat_gather1<<<gWave, 256, 0, stream>>>((const uint*)h2b, ssb, sdb, offs, srcs, b2, out, n);
}

// Round 17
// 210.852 us; speedup vs baseline: 1.0312x; 1.0312x over previous
//
#include <hip/hip_runtime.h>
#include <hip/hip_bf16.h>
#include <math.h>

#define NEG_SLOPE 0.2f
#define EPS_SM 1e-16f
#define BN_EPS 1e-5f
#define CHUNKS 256  // coarse-pass blocks

typedef __attribute__((ext_vector_type(8))) short bf16x8;
typedef __attribute__((ext_vector_type(4))) float f32x4;

__device__ __forceinline__ float lrelu(float x) { return x > 0.f ? x : NEG_SLOPE * x; }
// fp32 -> bf16 round-to-nearest-even
__device__ __forceinline__ ushort f2bf(float f) {
    uint u = __float_as_uint(f);
    return (ushort)((u + 0x7FFFu + ((u >> 16) & 1u)) >> 16);
}
__device__ __forceinline__ float bfl(uint u) { return __uint_as_float(u << 16); }
__device__ __forceinline__ float bfh(uint u) { return __uint_as_float(u & 0xFFFF0000u); }

// ---- pack W fp32 -> bf16 in B-fragment order; also zeros BN sums ----
__global__ void pack_w(const float* __restrict__ W0, const float* __restrict__ W1,
                       const float* __restrict__ W2, ushort* __restrict__ P0,
                       ushort* __restrict__ P1, ushort* __restrict__ P2,
                       float* __restrict__ sums) {
    int i = blockIdx.x * blockDim.x + threadIdx.x;
    if (i < 8192) sums[i] = 0.f;  // sumsP0 + sumsP1 (contiguous)
    const float* W;
    ushort* P;
    int NC, s;
    if (i < 16384) { W = W0; P = P0; NC = 128; s = i; }
    else if (i < 32768) { W = W1; P = P1; NC = 128; s = i - 16384; }
    else if (i < 34816) { W = W2; P = P2; NC = 16; s = i - 32768; }
    else return;
    int k = s / NC, col = s % NC;
    int CT = NC >> 4;
    int dst = (((k >> 5) * CT + (col >> 4)) << 9) +
              (((col & 15) | (((k >> 3) & 3) << 4)) << 3) + (k & 7);
    P[dst] = f2bf(W[s]);
}

// ================= zero-device-atomic CSR build (scan-free) =================
// The global prefix-scan dispatch is eliminated: each consumer block
// recomputes the tiny prefix quantities it needs from the 200KB hist array
// (L2-hot) — redundant recompute beats a serial single-block scan.

// scatter edges into bucket-major order; per-bucket cursor bases computed
// in-block: (exclusive scan of bucket totals) + (chunks < blk partial).
__global__ __launch_bounds__(256) void bucket_scatter(const int* __restrict__ src,
                                                      const int* __restrict__ dst, int E,
                                                      const int* __restrict__ hist,
                                                      uint* __restrict__ bpack, int nbuck) {
    __shared__ int cur[256];
    __shared__ int wsum[4];
    int blk = blockIdx.x, tid = threadIdx.x;
    int lane = tid & 63, w = tid >> 6;
    int total = 0, partial = 0;
    if (tid < nbuck) {
        const int4* hp = (const int4*)(hist + tid * CHUNKS);
        int nblk4 = blk >> 2;
#pragma unroll 8
        for (int c = 0; c < CHUNKS / 4; ++c) {
            int4 vv = hp[c];
            int s4 = vv.x + vv.y + vv.z + vv.w;
            total += s4;
            partial += (c < nblk4) ? s4 : 0;
        }
        for (int c = nblk4 * 4; c < blk; ++c) partial += hist[tid * CHUNKS + c];
    }
    // exclusive scan of per-bucket totals across the block (nbuck <= 256)
    int incl = total;
#pragma unroll
    for (int d = 1; d < 64; d <<= 1) {
        int t = __shfl_up(incl, d, 64);
        if (lane >= d) incl += t;
    }
    if (lane == 63) wsum[w] = incl;
    __syncthreads();
    int wbase = 0;
    for (int j = 0; j < w; ++j) wbase += wsum[j];
    if (tid < nbuck) cur[tid] = wbase + incl - total + partial;
    __syncthreads();
    int e0 = (int)(((long)E * blk) >> 8);
    int e1 = (int)(((long)E * (blk + 1)) >> 8);
    for (int i = e0 + tid; i < e1; i += 256) {
        int d = dst[i];
        int p = atomicAdd(&cur[d >> 8], 1);
        bpack[p] = ((uint)src[i] << 8) | (uint)(d & 255);
    }
}

// per-bucket fine CSR; ebase/eend recomputed in-block from hist.
__global__ __launch_bounds__(256) void fine_csr(const uint* __restrict__ bpack,
                                                const int* __restrict__ hist, int E, int n,
                                                int* __restrict__ offs, int* __restrict__ srcs,
                                                int nbuck) {
    __shared__ int cnt[256];
    __shared__ int wsum[4];
    __shared__ int sh_base, sh_tot;
    int bk = blockIdx.x, tid = threadIdx.x;
    int lane = tid & 63, w = tid >> 6;
    // ebase = sum of all hist entries of buckets < bk (block-strided reduce)
    int acc = 0;
    const int4* h4 = (const int4*)hist;
    int n4 = bk * (CHUNKS / 4);
    for (int i = tid; i < n4; i += 256) {
        int4 vv = h4[i];
        acc += vv.x + vv.y + vv.z + vv.w;
    }
#pragma unroll
    for (int d = 32; d >= 1; d >>= 1) acc += __shfl_xor(acc, d, 64);
    if (lane == 0) wsum[w] = acc;
    __syncthreads();
    if (tid == 0) sh_base = wsum[0] + wsum[1] + wsum[2] + wsum[3];
    __syncthreads();
    // bucket total (one chunk count per thread)
    int btr = hist[bk * CHUNKS + tid];
#pragma unroll
    for (int d = 32; d >= 1; d >>= 1) btr += __shfl_xor(btr, d, 64);
    if (lane == 0) wsum[w] = btr;
    __syncthreads();
    if (tid == 0) sh_tot = wsum[0] + wsum[1] + wsum[2] + wsum[3];
    __syncthreads();
    int ebase = sh_base;
    int eend = ebase + sh_tot;
    cnt[tid] = 0;
    __syncthreads();
    for (int i = ebase + tid; i < eend; i += 256) atomicAdd(&cnt[bpack[i] & 255], 1);
    __syncthreads();
    int v = cnt[tid];
    int incl = v;
#pragma unroll
    for (int d = 1; d < 64; d <<= 1) {
        int t = __shfl_up(incl, d, 64);
        if (lane >= d) incl += t;
    }
    if (lane == 63) wsum[w] = incl;
    __syncthreads();
    int wbase = 0;
    for (int j = 0; j < w; ++j) wbase += wsum[j];
    int excl = wbase + incl - v;
    int node = bk * 256 + tid;
    if (node < n) offs[node] = ebase + excl;
    cnt[tid] = ebase + excl;  // reuse as cursor
    __syncthreads();
    for (int i = ebase + tid; i < eend; i += 256) {
        uint pk = bpack[i];
        int p = atomicAdd(&cnt[pk & 255], 1);
        srcs[p] = (int)(pk >> 8);
    }
    if (bk == nbuck - 1 && tid == 0) offs[n] = E;
}

// ---- MFMA GEMM: 16 rows/block, ONE wave/block. B-frags from global (L1-hot).
// ---- Node-major h + scores. Optional bf16-X + fused BN+ELU staging; optional
// ---- coarse bucket histogram fused in leading CHUNKS blocks.
template <int NC, int HEADS, bool XBN, bool BCFUSE>
__global__ __launch_bounds__(64) void gemm_mfma(
    const void* __restrict__ Xv, const ushort* __restrict__ Wp, ushort* __restrict__ Hb,
    int n, const float* __restrict__ sumsP, const float* __restrict__ g,
    const float* __restrict__ be, const float* __restrict__ as_, const float* __restrict__ ad_,
    float* __restrict__ ss, float* __restrict__ sd,
    const int* __restrict__ dstE, int E, int* __restrict__ hist, int nbuck) {
    int tid = threadIdx.x;
    constexpr int CT = NC / 16;
    constexpr int FPH = NC / HEADS / 16;
    __shared__ __align__(16) ushort Xb[16 * 128];
    __shared__ float ssl[16 * HEADS], sdl[16 * HEADS];
    if constexpr (BCFUSE) {
        if ((int)blockIdx.x < CHUNKS) {  // coarse histogram, LDS atomics only
            int* h = (int*)Xb;
            for (int j = tid; j < 256; j += 64) h[j] = 0;
            __syncthreads();
            int blk = blockIdx.x;
            int e0 = (int)(((long)E * blk) >> 8);
            int e1 = (int)(((long)E * (blk + 1)) >> 8);
            for (int i = e0 + tid; i < e1; i += 64) atomicAdd(&h[dstE[i] >> 8], 1);
            __syncthreads();
            for (int j = tid; j < nbuck; j += 64) hist[j * CHUNKS + blk] = h[j];
            return;
        }
    }
    int bid = BCFUSE ? ((int)blockIdx.x - CHUNKS) : (int)blockIdx.x;
    int row0 = bid * 16;
    if constexpr (!XBN) {
        const float* X = (const float*)Xv;
#pragma unroll
        for (int i = 0; i < 8; ++i) {
            int idx = tid + i * 64;
            int row = idx >> 5, q = idx & 31;
            int gr = row0 + row;
            float4 v = make_float4(0.f, 0.f, 0.f, 0.f);
            if (gr < n) v = ((const float4*)(X + (long)gr * 128))[q];
            ushort4 p = make_ushort4(f2bf(v.x), f2bf(v.y), f2bf(v.z), f2bf(v.w));
            int s = (q >> 1) ^ (row & 15);
            *(ushort4*)&Xb[row * 128 + s * 8 + (q & 1) * 4] = p;
        }
    } else {
        const ushort* X = (const ushort*)Xv;
        int c8 = (tid & 15) * 8;
        float inv_n = 1.f / (float)n;
        float bm[8], bs[8], bb[8];
#pragma unroll
        for (int j = 0; j < 8; ++j) {
            int ch = c8 + j;
            float m = sumsP[ch * 16] * inv_n;
            float vv = fmaxf(sumsP[(128 + ch) * 16] * inv_n - m * m, 0.f);
            bm[j] = m;
            bs[j] = rsqrtf(vv + BN_EPS) * g[ch];
            bb[j] = be[ch];
        }
#pragma unroll
        for (int i = 0; i < 4; ++i) {
            int idx = tid + i * 64;
            int row = idx >> 4, g8 = idx & 15;
            int gr = row0 + row;
            uint4 v = make_uint4(0, 0, 0, 0);
            if (gr < n) v = ((const uint4*)(X + (long)gr * 128))[g8];
            float a, b;
#define BNE(comp, j0)                                                  \
    a = bfl(comp); b = bfh(comp);                                      \
    a = (a - bm[j0]) * bs[j0] + bb[j0]; a = a > 0.f ? a : expm1f(a);   \
    b = (b - bm[j0 + 1]) * bs[j0 + 1] + bb[j0 + 1];                    \
    b = b > 0.f ? b : expm1f(b);                                       \
    comp = (uint)f2bf(a) | ((uint)f2bf(b) << 16);
            BNE(v.x, 0) BNE(v.y, 2) BNE(v.z, 4) BNE(v.w, 6)
#undef BNE
            int s = g8 ^ (row & 15);
            *(uint4*)&Xb[row * 128 + s * 8] = v;
        }
    }
    __syncthreads();
    int lane = tid;
    int lrow = lane & 15, lhi = lane >> 4;
    f32x4 zero = {0.f, 0.f, 0.f, 0.f};
    f32x4 acc[CT];
#pragma unroll
    for (int f = 0; f < CT; ++f) acc[f] = zero;
    const ushort* xr = &Xb[lrow * 128];
#pragma unroll
    for (int ks = 0; ks < 4; ++ks) {
        int kg = ks * 4 + lhi;
        bf16x8 a = *(const bf16x8*)&xr[(kg ^ lrow) << 3];
#pragma unroll
        for (int f = 0; f < CT; ++f) {
            bf16x8 b = *(const bf16x8*)&Wp[((ks * CT + f) * 64 + lane) * 8];
            acc[f] = __builtin_amdgcn_mfma_f32_16x16x32_bf16(a, b, acc[f], 0, 0, 0);
        }
    }
    __syncthreads();
#pragma unroll
    for (int f = 0; f < CT; ++f)
#pragma unroll
        for (int j = 0; j < 4; ++j)
            Xb[(lhi * 4 + j) * NC + f * 16 + lrow] = f2bf(acc[f][j]);
    float asv[CT], adv[CT];
#pragma unroll
    for (int f = 0; f < CT; ++f) {
        asv[f] = as_[f * 16 + lrow];
        adv[f] = ad_[f * 16 + lrow];
    }
#pragma unroll
    for (int h = 0; h < HEADS; ++h) {
        float ps[4] = {}, pd[4] = {};
#pragma unroll
        for (int fi = 0; fi < FPH; ++fi) {
            int f = h * FPH + fi;
#pragma unroll
            for (int j = 0; j < 4; ++j) {
                ps[j] = fmaf(acc[f][j], asv[f], ps[j]);
                pd[j] = fmaf(acc[f][j], adv[f], pd[j]);
            }
        }
#pragma unroll
        for (int j = 0; j < 4; ++j) {
#pragma unroll
            for (int d = 1; d < 16; d <<= 1) {
                ps[j] += __shfl_xor(ps[j], d, 64);
                pd[j] += __shfl_xor(pd[j], d, 64);
            }
            if (lrow == 0) {
                ssl[(lhi * 4 + j) * HEADS + h] = ps[j];
                sdl[(lhi * 4 + j) * HEADS + h] = pd[j];
            }
        }
    }
    __syncthreads();
    constexpr int NU = 16 * NC / 8;
#pragma unroll
    for (int i = 0; i < (NU + 63) / 64; ++i) {
        int idx = tid + i * 64;
        if (idx < NU) {
            int row = idx / (NC / 8), c8i = idx % (NC / 8);
            int gr = row0 + row;
            if (gr < n) ((uint4*)&Hb[(long)gr * NC])[c8i] = ((const uint4*)Xb)[idx];
        }
    }
    if (tid < 16 * HEADS) {
        int row = tid / HEADS, hh = tid % HEADS;
        int gr = row0 + row;
        if (gr < n) {
            ss[(long)gr * HEADS + hh] = ssl[tid];
            sd[(long)gr * HEADS + hh] = sdl[tid];
        }
    }
}

// ---- GAT gather, 4 heads x 32ch (round-15 known-best): single pass,
// ---- 4 edge-groups x 16 lanes x 8ch, pair-unrolled.
__global__ __launch_bounds__(256) void gat_gather4(
    const uint* __restrict__ hb, const float* __restrict__ ss, const float* __restrict__ sd,
    const int* __restrict__ offs, const int* __restrict__ srcs,
    const float* __restrict__ bias, ushort* __restrict__ outb, int n) {
    int wid = threadIdx.x >> 6;
    int lane = threadIdx.x & 63;
    int node = blockIdx.x * 4 + wid;
    if (node >= n) return;
    int off = offs[node];
    int dg = offs[node + 1] - off;
    int grp = lane >> 4;
    int ll = lane & 15;
    int hd = ll >> 2;
    float sdn = sd[node * 4 + hd];
    float es = lrelu(ss[node * 4 + hd] + sdn);
    const uint* hrow = hb + ll * 4;
    float acc[8] = {};
    float sm = 0.f;
    int i = grp;
    for (; i + 4 < dg; i += 8) {
        int s0 = srcs[off + i];
        int s1 = srcs[off + i + 4];
        float w0 = __expf(lrelu(ss[s0 * 4 + hd] + sdn));
        float w1 = __expf(lrelu(ss[s1 * 4 + hd] + sdn));
        uint4 h0 = *(const uint4*)(hrow + (long)s0 * 64);
        uint4 h1 = *(const uint4*)(hrow + (long)s1 * 64);
        sm += w0 + w1;
        acc[0] = fmaf(w0, bfl(h0.x), acc[0]); acc[0] = fmaf(w1, bfl(h1.x), acc[0]);
        acc[1] = fmaf(w0, bfh(h0.x), acc[1]); acc[1] = fmaf(w1, bfh(h1.x), acc[1]);
        acc[2] = fmaf(w0, bfl(h0.y), acc[2]); acc[2] = fmaf(w1, bfl(h1.y), acc[2]);
        acc[3] = fmaf(w0, bfh(h0.y), acc[3]); acc[3] = fmaf(w1, bfh(h1.y), acc[3]);
        acc[4] = fmaf(w0, bfl(h0.z), acc[4]); acc[4] = fmaf(w1, bfl(h1.z), acc[4]);
        acc[5] = fmaf(w0, bfh(h0.z), acc[5]); acc[5] = fmaf(w1, bfh(h1.z), acc[5]);
        acc[6] = fmaf(w0, bfl(h0.w), acc[6]); acc[6] = fmaf(w1, bfl(h1.w), acc[6]);
        acc[7] = fmaf(w0, bfh(h0.w), acc[7]); acc[7] = fmaf(w1, bfh(h1.w), acc[7]);
    }
    for (; i < dg; i += 4) {
        int s = srcs[off + i];
        float w = __expf(lrelu(ss[s * 4 + hd] + sdn));
        sm += w;
        uint4 hv = *(const uint4*)(hrow + (long)s * 64);
        acc[0] = fmaf(w, bfl(hv.x), acc[0]);
        acc[1] = fmaf(w, bfh(hv.x), acc[1]);
        acc[2] = fmaf(w, bfl(hv.y), acc[2]);
        acc[3] = fmaf(w, bfh(hv.y), acc[3]);
        acc[4] = fmaf(w, bfl(hv.z), acc[4]);
        acc[5] = fmaf(w, bfh(hv.z), acc[5]);
        acc[6] = fmaf(w, bfl(hv.w), acc[6]);
        acc[7] = fmaf(w, bfh(hv.w), acc[7]);
    }
#pragma unroll
    for (int j = 0; j < 8; ++j) {
        acc[j] += __shfl_xor(acc[j], 16, 64);
        acc[j] += __shfl_xor(acc[j], 32, 64);
    }
    sm += __shfl_xor(sm, 16, 64);
    sm += __shfl_xor(sm, 32, 64);
    float wS = __expf(es);
    sm += wS;
    uint4 hvS = *(const uint4*)(hrow + (long)node * 64);
    acc[0] = fmaf(wS, bfl(hvS.x), acc[0]);
    acc[1] = fmaf(wS, bfh(hvS.x), acc[1]);
    acc[2] = fmaf(wS, bfl(hvS.y), acc[2]);
    acc[3] = fmaf(wS, bfh(hvS.y), acc[3]);
    acc[4] = fmaf(wS, bfl(hvS.z), acc[4]);
    acc[5] = fmaf(wS, bfh(hvS.z), acc[5]);
    acc[6] = fmaf(wS, bfl(hvS.w), acc[6]);
    acc[7] = fmaf(wS, bfh(hvS.w), acc[7]);
    float inv = 1.f / (sm + EPS_SM);
    if (grp == 0) {
        float4 bA = *(const float4*)&bias[ll * 8];
        float4 bB = *(const float4*)&bias[ll * 8 + 4];
        uint4 p;
        p.x = (uint)f2bf(acc[0] * inv + bA.x) | ((uint)f2bf(acc[1] * inv + bA.y) << 16);
        p.y = (uint)f2bf(acc[2] * inv + bA.z) | ((uint)f2bf(acc[3] * inv + bA.w) << 16);
        p.z = (uint)f2bf(acc[4] * inv + bB.x) | ((uint)f2bf(acc[5] * inv + bB.y) << 16);
        p.w = (uint)f2bf(acc[6] * inv + bB.z) | ((uint)f2bf(acc[7] * inv + bB.w) << 16);
        *(uint4*)&outb[(long)node * 128 + ll * 8] = p;
    }
}

// ---- GAT gather, 1 head x 16ch (round-15 variant) ----
__global__ __launch_bounds__(256) void gat_gather1(
    const uint* __restrict__ hb2, const float* __restrict__ ss, const float* __restrict__ sd,
    const int* __restrict__ offs, const int* __restrict__ srcs,
    const float* __restrict__ bias, float* __restrict__ out, int n) {
    int wid = threadIdx.x >> 6;
    int lane = threadIdx.x & 63;
    int node = blockIdx.x * 4 + wid;
    if (node >= n) return;
    int off = offs[node];
    int dg = offs[node + 1] - off;
    int grp = lane >> 3;
    int ll = lane & 7;
    float sdn = sd[node];
    float es = lrelu(ss[node] + sdn);
    float a0 = 0.f, a1 = 0.f, sm = 0.f;
    int i = grp;
    for (; i + 8 < dg; i += 16) {
        int s0 = srcs[off + i];
        int s1 = srcs[off + i + 8];
        float w0 = __expf(lrelu(ss[s0] + sdn));
        float w1 = __expf(lrelu(ss[s1] + sdn));
        uint h0 = hb2[s0 * 8 + ll];
        uint h1 = hb2[s1 * 8 + ll];
        sm += w0 + w1;
        a0 = fmaf(w0, bfl(h0), a0); a0 = fmaf(w1, bfl(h1), a0);
        a1 = fmaf(w0, bfh(h0), a1); a1 = fmaf(w1, bfh(h1), a1);
    }
    for (; i < dg; i += 8) {
        int s = srcs[off + i];
        float w = __expf(lrelu(ss[s] + sdn));
        sm += w;
        uint hv = hb2[s * 8 + ll];
        a0 = fmaf(w, bfl(hv), a0);
        a1 = fmaf(w, bfh(hv), a1);
    }
#pragma unroll
    for (int d = 8; d <= 32; d <<= 1) {
        a0 += __shfl_xor(a0, d, 64);
        a1 += __shfl_xor(a1, d, 64);
        sm += __shfl_xor(sm, d, 64);
    }
    float wS = __expf(es);
    sm += wS;
    uint hvS = hb2[node * 8 + ll];
    a0 = fmaf(wS, bfl(hvS), a0);
    a1 = fmaf(wS, bfh(hvS), a1);
    float inv = 1.f / (sm + EPS_SM);
    if (grp == 0) {
        float2 o = make_float2(a0 * inv + bias[ll * 2], a1 * inv + bias[ll * 2 + 1]);
        *(float2*)&out[(long)node * 16 + ll * 2] = o;
    }
}

// ---- BatchNorm stats (bf16 input) ----
__global__ __launch_bounds__(256) void bn_stats_bf16(const uint4* __restrict__ X4,
                                                     float* __restrict__ sumsP, int n) {
    __shared__ float red[4096];
    int tid = threadIdx.x;
    float s[8] = {}, s2[8] = {};
    long tot = (long)n * 16;
    long T = (long)gridDim.x * 256;
    for (long i = (long)blockIdx.x * 256 + tid; i < tot; i += T) {
        uint4 v = X4[i];
        float f;
        f = bfl(v.x); s[0] += f; s2[0] = fmaf(f, f, s2[0]);
        f = bfh(v.x); s[1] += f; s2[1] = fmaf(f, f, s2[1]);
        f = bfl(v.y); s[2] += f; s2[2] = fmaf(f, f, s2[2]);
        f = bfh(v.y); s[3] += f; s2[3] = fmaf(f, f, s2[3]);
        f = bfl(v.z); s[4] += f; s2[4] = fmaf(f, f, s2[4]);
        f = bfh(v.z); s[5] += f; s2[5] = fmaf(f, f, s2[5]);
        f = bfl(v.w); s[6] += f; s2[6] = fmaf(f, f, s2[6]);
        f = bfh(v.w); s[7] += f; s2[7] = fmaf(f, f, s2[7]);
    }
#pragma unroll
    for (int j = 0; j < 8; ++j) {
        red[j * 256 + tid] = s[j];
        red[(8 + j) * 256 + tid] = s2[j];
    }
    __syncthreads();
    int ch = tid & 127, st = tid >> 7;
    int base = (st * 8 + (ch & 7)) * 256 + (ch >> 3);
    float a = 0.f;
#pragma unroll
    for (int rep = 0; rep < 16; ++rep) a += red[base + rep * 16];
    atomicAdd(&sumsP[tid * 16], a);
}

extern "C" void kernel_launch(void* const* d_in, const int* in_sizes, int n_in,
                              void* d_out, int out_size, void* d_ws, size_t ws_size,
                              hipStream_t stream) {
    const float* x = (const float*)d_in[0];
    const int* ei = (const int*)d_in[1];
    const float* W0 = (const float*)d_in[2];
    const float* as0 = (const float*)d_in[3];
    const float* ad0 = (const float*)d_in[4];
    const float* b0 = (const float*)d_in[5];
    const float* g0 = (const float*)d_in[6];
    const float* be0 = (const float*)d_in[7];
    const float* W1 = (const float*)d_in[8];
    const float* as1 = (const float*)d_in[9];
    const float* ad1 = (const float*)d_in[10];
    const float* b1 = (const float*)d_in[11];
    const float* g1 = (const float*)d_in[12];
    const float* be1 = (const float*)d_in[13];
    const float* W2 = (const float*)d_in[14];
    const float* as2 = (const float*)d_in[15];
    const float* ad2 = (const float*)d_in[16];
    const float* b2 = (const float*)d_in[17];

    int n = in_sizes[0] / 128;
    int E = in_sizes[1] / 2;
    const int* srcA = ei;
    const int* dstA = ei + E;
    int nbuck = (n + 255) >> 8;

    char* base = (char*)d_ws;
    auto alloc = [&](size_t bytes) {
        char* p = base;
        base += (bytes + 255) & ~(size_t)255;
        return p;
    };
    ushort* hb = (ushort*)alloc((size_t)n * 128 * 2);
    ushort* actb = (ushort*)alloc((size_t)n * 128 * 2);
    ushort* h2b = (ushort*)alloc((size_t)n * 16 * 2);
    float* ssb = (float*)alloc((size_t)n * 4 * 4);
    float* sdb = (float*)alloc((size_t)n * 4 * 4);
    float* sumsP0 = (float*)alloc(4096 * 4);
    float* sumsP1 = (float*)alloc(4096 * 4);
    int* hist = (int*)alloc((size_t)nbuck * CHUNKS * 4);
    uint* bpack = (uint*)alloc((size_t)E * 4);
    int* offs = (int*)alloc(((size_t)n + 1) * 4);
    int* srcs = (int*)alloc((size_t)E * 4);
    ushort* Wp0 = (ushort*)alloc(16384 * 2);
    ushort* Wp1 = (ushort*)alloc(16384 * 2);
    ushort* Wp2 = (ushort*)alloc(2048 * 2);

    float* out = (float*)d_out;

    pack_w<<<136, 256, 0, stream>>>(W0, W1, W2, Wp0, Wp1, Wp2, sumsP0);

    int gGemm = (n + 15) / 16;
    int gWave = (n + 3) / 4;

    // ---- layer 0 GEMM (fp32 X) + fused coarse bucket histogram ----
    gemm_mfma<128, 4, false, true><<<CHUNKS + gGemm, 64, 0, stream>>>(
        x, Wp0, hb, n, nullptr, g0, be0, as0, ad0, ssb, sdb, dstA, E, hist, nbuck);
    bucket_scatter<<<CHUNKS, 256, 0, stream>>>(srcA, dstA, E, hist, bpack, nbuck);
    fine_csr<<<nbuck, 256, 0, stream>>>(bpack, hist, E, n, offs, srcs, nbuck);

    gat_gather4<<<gWave, 256, 0, stream>>>((const uint*)hb, ssb, sdb, offs, srcs, b0, actb, n);
    bn_stats_bf16<<<256, 256, 0, stream>>>((const uint4*)actb, sumsP0, n);

    // ---- layer 1 (BN+ELU fused into bf16 GEMM staging) ----
    gemm_mfma<128, 4, true, false><<<gGemm, 64, 0, stream>>>(
        actb, Wp1, hb, n, sumsP0, g0, be0, as1, ad1, ssb, sdb, nullptr, 0, nullptr, 0);
    gat_gather4<<<gWave, 256, 0, stream>>>((const uint*)hb, ssb, sdb, offs, srcs, b1, actb, n);
    bn_stats_bf16<<<256, 256, 0, stream>>>((const uint4*)actb, sumsP1, n);

    // ---- layer 2 ----
    gemm_mfma<16, 1, true, false><<<gGemm, 64, 0, stream>>>(
        actb, Wp2, h2b, n, sumsP1, g1, be1, as2, ad2, ssb, sdb, nullptr, 0, nullptr, 0);
    gat_gather1<<<gWave, 256, 0, stream>>>((const uint*)h2b, ssb, sdb, offs, srcs, b2, out, n);
}